// Round 2
// baseline (19234.013 us; speedup 1.0000x reference)
//
#include <hip/hip_runtime.h>
#include <cstdint>

#define TT 512

typedef float f32x16 __attribute__((ext_vector_type(16)));
typedef short s16x8 __attribute__((ext_vector_type(8)));
typedef unsigned short u16x4 __attribute__((ext_vector_type(4)));

// ---------------- threefry2x32 (exact JAX semantics) ----------------
__host__ __device__ inline void tf2x32(uint32_t k0, uint32_t k1, uint32_t& x0, uint32_t& x1) {
  uint32_t k2 = k0 ^ k1 ^ 0x1BD11BDAu;
#define TF_R(r) { x0 += x1; x1 = (x1 << r) | (x1 >> (32 - r)); x1 ^= x0; }
  x0 += k0; x1 += k1;
  TF_R(13) TF_R(15) TF_R(26) TF_R(6)
  x0 += k1; x1 += k2 + 1u;
  TF_R(17) TF_R(29) TF_R(16) TF_R(24)
  x0 += k2; x1 += k0 + 2u;
  TF_R(13) TF_R(15) TF_R(26) TF_R(6)
  x0 += k0; x1 += k1 + 3u;
  TF_R(17) TF_R(29) TF_R(16) TF_R(24)
  x0 += k1; x1 += k2 + 4u;
  TF_R(13) TF_R(15) TF_R(26) TF_R(6)
  x0 += k2; x1 += k0 + 5u;
#undef TF_R
}

struct KParams {
  const float* input;
  const float* w_ih[4];
  const float* w_hh[4];
  const float* b_ih[4];
  const float* b_hh[4];
  const float* w_lin;
  const float* b_lin;
  unsigned short* hbuf;   // 16 buffers x (hi 32768 | lo 32768) ushorts = 2 MB
  uint32_t* flags;        // [4][2][512][32]
  float* out;             // [128][512]
  uint32_t mk[4][2];      // per-layer threefry subkeys (partitionable split)
};

__device__ __forceinline__ unsigned short f2bf(float v) {
  uint32_t u = __float_as_uint(v);
  u += 0x7FFFu + ((u >> 16) & 1u);      // RNE
  return (unsigned short)(u >> 16);
}
__device__ __forceinline__ float bf2f(unsigned short b) {
  return __uint_as_float(((uint32_t)b) << 16);
}
__device__ __forceinline__ float sigm(float x) { return 1.f / (1.f + __expf(-x)); }
__device__ __forceinline__ float tanh_fast(float x) {
  float a = fabsf(x);
  float e = __expf(-2.f * a);
  float r = (1.f - e) / (1.f + e);
  return copysignf(r, x);
}

#define MFMA(A, Bv, C) __builtin_amdgcn_mfma_f32_32x32x16_bf16((A), (Bv), (C), 0, 0, 0)

__global__ __launch_bounds__(256, 1) void lstm4(KParams P) {
  const int wg   = blockIdx.x;
  const int grp  = wg & 7;       // XCD-affinity group: (layer, half)
  const int iwg  = wg >> 3;      // 0..31: which 16-unit slice
  const int l    = grp >> 1;
  const int p    = grp & 1;
  const int tid  = threadIdx.x;
  const int wave = tid >> 6;
  const int lane = tid & 63;

  __shared__ float part[4][32][64];   // 32 KB: per-wave partial gate sums, one mtile chunk at a time
  __shared__ float bias_s[64];
  __shared__ float wih1_s[64];
  __shared__ float wlin_s[16];
  __shared__ float red_s[4][64];

  // ---- init: per-wave weight fragments (hi/lo bf16) into registers ----
  // local rows: [0..15]=i, [16..31]=f (mtile0); [32..47]=g, [48..63]=o (mtile1)
  // wave k-split: frag ji covers global kstep blk=(ji&7)*4+wave
  s16x8 Whi[2][16], Wlo[2][16];
  {
#pragma unroll
    for (int ji = 0; ji < 16; ++ji) {
      const bool valid = (l > 0) || (ji < 8);   // layer0 only has K=512 (own h)
      const float* wsrc = (l == 0 || ji >= 8) ? P.w_hh[l] : P.w_ih[l];
      const int blk = (ji & 7) * 4 + wave;
      const int col = blk * 16 + (lane >> 5) * 8;
#pragma unroll
      for (int m = 0; m < 2; ++m) {
        const int rl = m * 32 + (lane & 31);
        const int grow = (rl >> 4) * 512 + iwg * 16 + (rl & 15);
        s16x8 h8 = {0, 0, 0, 0, 0, 0, 0, 0};
        s16x8 l8 = {0, 0, 0, 0, 0, 0, 0, 0};
        if (valid) {
          const float* s = wsrc + grow * 512 + col;
#pragma unroll
          for (int e = 0; e < 8; ++e) {
            float v = s[e];
            unsigned short hb = f2bf(v);
            h8[e] = (short)hb;
            l8[e] = (short)f2bf(v - bf2f(hb));
          }
        }
        Whi[m][ji] = h8;
        Wlo[m][ji] = l8;
      }
    }
  }
  if (tid < 64) {
    const int rl = tid;
    const int grow = (rl >> 4) * 512 + iwg * 16 + (rl & 15);
    bias_s[rl] = P.b_ih[l][grow] + P.b_hh[l][grow];
    wih1_s[rl] = (l == 0) ? P.w_ih[0][grow] : 0.f;
  }
  if (l == 3 && tid < 16) wlin_s[tid] = P.w_lin[iwg * 16 + tid];
  __syncthreads();

  const int gb = p * 64 + lane;                 // global batch index for ew phase
  const uint32_t kk0 = P.mk[l][0], kk1 = P.mk[l][1];
  float cst[4] = {0.f, 0.f, 0.f, 0.f};          // cell state: 4 units (wave*4+cc), batch=lane

  for (int t = 0; t < TT; ++t) {
    // ---------- wait on producer/consumer flags ----------
    {
      const uint32_t* fp = nullptr;
      if (wave == 0 && l > 0)                     fp = P.flags + (((l - 1) * 2 + p) * TT + t) * 32;
      else if (wave == 1 && t > 0)                fp = P.flags + ((l * 2 + p) * TT + (t - 1)) * 32;
      else if (wave == 2 && l < 3 && t >= 2)      fp = P.flags + (((l + 1) * 2 + p) * TT + (t - 2)) * 32;
      if (fp) {
        while (true) {
          uint32_t v = (lane < 32)
              ? __hip_atomic_load(fp + lane, __ATOMIC_RELAXED, __HIP_MEMORY_SCOPE_AGENT)
              : 1u;
          if (__all(v != 0)) break;
          __builtin_amdgcn_s_sleep(4);
        }
      }
    }
    __syncthreads();
    __builtin_amdgcn_fence(__ATOMIC_ACQUIRE, "agent");

    float xin = 0.f;
    if (l == 0) xin = P.input[gb * 512 + t];

    // ---------- GEMM: gates[64 rows, 64 batch] ----------
    f32x16 a00 = {0,0,0,0,0,0,0,0,0,0,0,0,0,0,0,0};
    f32x16 a01 = {0,0,0,0,0,0,0,0,0,0,0,0,0,0,0,0};
    f32x16 a10 = {0,0,0,0,0,0,0,0,0,0,0,0,0,0,0,0};
    f32x16 a11 = {0,0,0,0,0,0,0,0,0,0,0,0,0,0,0,0};

#define GEMM8(BUF, FB) { \
      _Pragma("unroll") \
      for (int jj = 0; jj < 8; ++jj) { \
        const int blk = jj * 4 + wave; \
        const unsigned short* bp = (BUF) + blk * 1024 + lane * 8; \
        s16x8 b0h = *(const s16x8*)(bp); \
        s16x8 b1h = *(const s16x8*)(bp + 512); \
        s16x8 b0l = *(const s16x8*)(bp + 32768); \
        s16x8 b1l = *(const s16x8*)(bp + 33280); \
        a00 = MFMA(Whi[0][jj + FB], b0h, a00); \
        a10 = MFMA(Whi[1][jj + FB], b0h, a10); \
        a01 = MFMA(Whi[0][jj + FB], b1h, a01); \
        a11 = MFMA(Whi[1][jj + FB], b1h, a11); \
        a00 = MFMA(Wlo[0][jj + FB], b0h, a00); \
        a10 = MFMA(Wlo[1][jj + FB], b0h, a10); \
        a01 = MFMA(Wlo[0][jj + FB], b1h, a01); \
        a11 = MFMA(Wlo[1][jj + FB], b1h, a11); \
        a00 = MFMA(Whi[0][jj + FB], b0l, a00); \
        a10 = MFMA(Whi[1][jj + FB], b0l, a10); \
        a01 = MFMA(Whi[0][jj + FB], b1l, a01); \
        a11 = MFMA(Whi[1][jj + FB], b1l, a11); \
      } }

    if (l > 0) {
      const unsigned short* bl_ = P.hbuf + (size_t)((((l - 1) * 2 + p) * 2) + (t & 1)) * 65536;
      GEMM8(bl_, 0);
      if (t > 0) {
        const unsigned short* ow = P.hbuf + (size_t)(((l * 2 + p) * 2) + ((t - 1) & 1)) * 65536;
        GEMM8(ow, 8);
      }
    } else if (t > 0) {
      const unsigned short* ow = P.hbuf + (size_t)(((0 * 2 + p) * 2) + ((t - 1) & 1)) * 65536;
      GEMM8(ow, 0);
    }
#undef GEMM8

    // ---------- cross-wave reduction (k-split partials), chunk 0 = rows 0..31 (i,f) ----------
#pragma unroll
    for (int nt = 0; nt < 2; ++nt)
#pragma unroll
      for (int r = 0; r < 16; ++r) {
        const int row = (r & 3) + 8 * (r >> 2) + 4 * (lane >> 5);
        part[wave][row][nt * 32 + (lane & 31)] = (nt == 0) ? a00[r] : a01[r];
      }
    __syncthreads();
    float si[4], sf[4];
#pragma unroll
    for (int cc = 0; cc < 4; ++cc) {
      const int ul = wave * 4 + cc;
      si[cc] = part[0][ul][lane] + part[1][ul][lane] + part[2][ul][lane] + part[3][ul][lane];
      sf[cc] = part[0][16 + ul][lane] + part[1][16 + ul][lane] + part[2][16 + ul][lane] + part[3][16 + ul][lane];
    }
    __syncthreads();
    // chunk 1 = rows 32..63 (g,o)
#pragma unroll
    for (int nt = 0; nt < 2; ++nt)
#pragma unroll
      for (int r = 0; r < 16; ++r) {
        const int row = (r & 3) + 8 * (r >> 2) + 4 * (lane >> 5);
        part[wave][row][nt * 32 + (lane & 31)] = (nt == 0) ? a10[r] : a11[r];
      }
    __syncthreads();
    float sg[4], so[4];
#pragma unroll
    for (int cc = 0; cc < 4; ++cc) {
      const int ul = wave * 4 + cc;
      sg[cc] = part[0][ul][lane] + part[1][ul][lane] + part[2][ul][lane] + part[3][ul][lane];
      so[cc] = part[0][16 + ul][lane] + part[1][16 + ul][lane] + part[2][16 + ul][lane] + part[3][16 + ul][lane];
    }

    // ---------- elementwise: LSTM cell + exact dropout mask ----------
    // JAX threefry_partitionable=True semantics (modern default):
    //   bits32[j] = out0 ^ out1 of threefry(subkey, (hi32(j)=0, lo32(j)=j))
    //   keep (mask=2) iff top bit == 0  (uniform<0.5)
    float hvec[4];
    float osum = 0.f;
#pragma unroll
    for (int cc = 0; cc < 4; ++cc) {
      const int ul = wave * 4 + cc;
      float pi = si[cc] + bias_s[ul];
      float pf = sf[cc] + bias_s[16 + ul];
      float pg = sg[cc] + bias_s[32 + ul];
      float po = so[cc] + bias_s[48 + ul];
      if (l == 0) {
        pi += wih1_s[ul] * xin;
        pf += wih1_s[16 + ul] * xin;
        pg += wih1_s[32 + ul] * xin;
        po += wih1_s[48 + ul] * xin;
      }
      float ig = sigm(pi), fg = sigm(pf), gg = tanh_fast(pg), og = sigm(po);
      float cn = fg * cst[cc] + ig * gg;
      cst[cc] = cn;
      float hh = og * tanh_fast(cn);
      const int gu = iwg * 16 + ul;
      uint32_t j = ((uint32_t)t * 128u + (uint32_t)gb) * 512u + (uint32_t)gu;
      uint32_t x0 = 0u;
      uint32_t x1 = j;
      tf2x32(kk0, kk1, x0, x1);
      uint32_t bits = x0 ^ x1;
      hh = (bits & 0x80000000u) ? 0.f : (hh * 2.f);
      hvec[cc] = hh;
      if (l == 3) osum += hh * wlin_s[ul];
    }

    // ---------- write h (hi/lo bf16, MFMA-B blocked layout) ----------
    {
      u16x4 hv, lv;
#pragma unroll
      for (int cc = 0; cc < 4; ++cc) {
        unsigned short hb = f2bf(hvec[cc]);
        hv[cc] = hb;
        lv[cc] = f2bf(hvec[cc] - bf2f(hb));
      }
      unsigned short* wb = P.hbuf + (size_t)(((l * 2 + p) * 2) + (t & 1)) * 65536;
      const int elem = ((iwg * 2 + (lane >> 5)) * 64 + (wave >> 1) * 32 + (lane & 31)) * 8 + (wave & 1) * 4;
      *(u16x4*)(wb + elem) = hv;
      *(u16x4*)(wb + 32768 + elem) = lv;
    }

    // ---------- layer-3: output projection ----------
    if (l == 3) {
      red_s[wave][lane] = osum;
      __syncthreads();
      if (tid < 64) {
        float v = red_s[0][tid] + red_s[1][tid] + red_s[2][tid] + red_s[3][tid];
        if (iwg == 0) v += P.b_lin[0];
        atomicAdd(&P.out[(p * 64 + tid) * 512 + t], v);
      }
    }

    // ---------- publish ----------
    __builtin_amdgcn_fence(__ATOMIC_RELEASE, "agent");
    __syncthreads();
    if (tid == 0)
      __hip_atomic_store(P.flags + ((l * 2 + p) * TT + t) * 32 + iwg, 1u,
                         __ATOMIC_RELAXED, __HIP_MEMORY_SCOPE_AGENT);
  }
}

extern "C" void kernel_launch(void* const* d_in, const int* in_sizes, int n_in,
                              void* d_out, int out_size, void* d_ws, size_t ws_size,
                              hipStream_t stream) {
  (void)in_sizes; (void)n_in; (void)ws_size;
  KParams P;
  P.input = (const float*)d_in[0];
  for (int l = 0; l < 4; ++l) {
    P.w_ih[l] = (const float*)d_in[1 + 4 * l];
    P.w_hh[l] = (const float*)d_in[2 + 4 * l];
    P.b_ih[l] = (const float*)d_in[3 + 4 * l];
    P.b_hh[l] = (const float*)d_in[4 + 4 * l];
  }
  P.w_lin = (const float*)d_in[17];
  P.b_lin = (const float*)d_in[18];
  unsigned char* ws = (unsigned char*)d_ws;
  P.hbuf  = (unsigned short*)ws;                 // 2 MB
  P.flags = (uint32_t*)(ws + (2u << 20));        // 512 KB
  P.out   = (float*)d_out;

  // subkeys = jax.random.split(key(42), 4) under threefry_partitionable=True:
  // child[i] = full threefry output (both words) at counter (0, i)
  for (uint32_t i = 0; i < 4; ++i) {
    uint32_t x0 = 0u, x1 = i;
    tf2x32(0u, 42u, x0, x1);
    P.mk[i][0] = x0; P.mk[i][1] = x1;
  }

  hipMemsetAsync(P.flags, 0, 4 * 2 * 512 * 32 * sizeof(uint32_t), stream);
  hipMemsetAsync(d_out, 0, (size_t)out_size * sizeof(float), stream);
  hipLaunchKernelGGL(lstm4, dim3(256), dim3(256), 0, stream, P);
}

// Round 3
// 3549.622 us; speedup vs baseline: 5.4186x; 5.4186x over previous
//
#include <hip/hip_runtime.h>
#include <cstdint>

#define TT 512

typedef float f32x16 __attribute__((ext_vector_type(16)));
typedef short s16x8 __attribute__((ext_vector_type(8)));
typedef unsigned short u16x4 __attribute__((ext_vector_type(4)));

// ---------------- threefry2x32 (exact JAX semantics) ----------------
__host__ __device__ inline void tf2x32(uint32_t k0, uint32_t k1, uint32_t& x0, uint32_t& x1) {
  uint32_t k2 = k0 ^ k1 ^ 0x1BD11BDAu;
#define TF_R(r) { x0 += x1; x1 = (x1 << r) | (x1 >> (32 - r)); x1 ^= x0; }
  x0 += k0; x1 += k1;
  TF_R(13) TF_R(15) TF_R(26) TF_R(6)
  x0 += k1; x1 += k2 + 1u;
  TF_R(17) TF_R(29) TF_R(16) TF_R(24)
  x0 += k2; x1 += k0 + 2u;
  TF_R(13) TF_R(15) TF_R(26) TF_R(6)
  x0 += k0; x1 += k1 + 3u;
  TF_R(17) TF_R(29) TF_R(16) TF_R(24)
  x0 += k1; x1 += k2 + 4u;
  TF_R(13) TF_R(15) TF_R(26) TF_R(6)
  x0 += k2; x1 += k0 + 5u;
#undef TF_R
}

struct KParams {
  const float* input;
  const float* w_ih[4];
  const float* w_hh[4];
  const float* b_ih[4];
  const float* b_hh[4];
  const float* w_lin;
  const float* b_lin;
  unsigned short* hbuf;   // 16 buffers x 32768 ushorts (bf16 hi only) = 1 MB
  uint32_t* flags;        // [4][2][512][32]
  float* out;             // [128][512]
  uint32_t mk[4][2];      // per-layer threefry subkeys (partitionable split)
};

__device__ __forceinline__ unsigned short f2bf(float v) {
  uint32_t u = __float_as_uint(v);
  u += 0x7FFFu + ((u >> 16) & 1u);      // RNE
  return (unsigned short)(u >> 16);
}
__device__ __forceinline__ float bf2f(unsigned short b) {
  return __uint_as_float(((uint32_t)b) << 16);
}
__device__ __forceinline__ float sigm(float x) { return 1.f / (1.f + __expf(-x)); }
__device__ __forceinline__ float tanh_fast(float x) {
  float a = fabsf(x);
  float e = __expf(-2.f * a);
  float r = (1.f - e) / (1.f + e);
  return copysignf(r, x);
}

#define MFMA(A, Bv, C) __builtin_amdgcn_mfma_f32_32x32x16_bf16((A), (Bv), (C), 0, 0, 0)

// counted vmcnt wait (a = iterations still in flight beyond the one we need; 2 loads/iter)
__device__ __forceinline__ void vmwait_dyn(int a) {
  switch (a) {
    case 0: asm volatile("s_waitcnt vmcnt(0)" ::: "memory"); break;
    case 1: asm volatile("s_waitcnt vmcnt(2)" ::: "memory"); break;
    case 2: asm volatile("s_waitcnt vmcnt(4)" ::: "memory"); break;
    case 3: asm volatile("s_waitcnt vmcnt(6)" ::: "memory"); break;
    case 4: asm volatile("s_waitcnt vmcnt(8)" ::: "memory"); break;
    case 5: asm volatile("s_waitcnt vmcnt(10)" ::: "memory"); break;
    case 6: asm volatile("s_waitcnt vmcnt(12)" ::: "memory"); break;
    case 7: asm volatile("s_waitcnt vmcnt(14)" ::: "memory"); break;
    default: asm volatile("s_waitcnt vmcnt(16)" ::: "memory"); break;
  }
  __builtin_amdgcn_sched_barrier(0);
}

#define ISSUE_LD(s0, s1, ptr) \
  asm volatile("global_load_dwordx4 %0, %2, off sc0 sc1\n\t" \
               "global_load_dwordx4 %1, %2, off offset:1024 sc0 sc1" \
               : "=&v"(s0), "=&v"(s1) : "v"(ptr) : "memory")

// NIT=16: i<8 from buf0 (below, frags 0..7), i>=8 from buf1 (own, frags 8..15)
// NIT=8 : all from buf0, frags 0..7
template <int NIT>
__device__ __forceinline__ void run_gemm(const unsigned short* buf0,
                                         const unsigned short* buf1,
                                         const s16x8 (&Whi)[2][16], const s16x8 (&Wlo)[2][16],
                                         int wave, int lane,
                                         f32x16& a00, f32x16& a01, f32x16& a10, f32x16& a11) {
  constexpr int D = 8;
  constexpr int S = D + 1;                  // extra slot: issue target never aliases pending read
  s16x8 st[S][2];
  const int lofs = wave * 1024 + lane * 8;  // blk = (i&7)*4 + wave; elem = blk*1024 + lane*8
#pragma unroll
  for (int i = 0; i < ((NIT < D) ? NIT : D); ++i) {
    const unsigned short* p = ((NIT == 16 && i >= 8) ? buf1 : buf0) + (i & 7) * 4096 + lofs;
    ISSUE_LD(st[i % S][0], st[i % S][1], p);
  }
#pragma unroll
  for (int i = 0; i < NIT; ++i) {
    if (i + D < NIT) {
      const int k = i + D;
      const unsigned short* p = ((NIT == 16 && k >= 8) ? buf1 : buf0) + (k & 7) * 4096 + lofs;
      ISSUE_LD(st[k % S][0], st[k % S][1], p);
    }
    vmwait_dyn((NIT - 1 - i < D) ? (NIT - 1 - i) : D);
    s16x8 bh0 = st[i % S][0];
    s16x8 bh1 = st[i % S][1];
    a00 = MFMA(Whi[0][i], bh0, a00);
    a10 = MFMA(Whi[1][i], bh0, a10);
    a01 = MFMA(Whi[0][i], bh1, a01);
    a11 = MFMA(Whi[1][i], bh1, a11);
    a00 = MFMA(Wlo[0][i], bh0, a00);
    a10 = MFMA(Wlo[1][i], bh0, a10);
    a01 = MFMA(Wlo[0][i], bh1, a01);
    a11 = MFMA(Wlo[1][i], bh1, a11);
  }
}

__global__ __launch_bounds__(256, 1) void lstm4(KParams P) {
  const int wg   = blockIdx.x;
  const int grp  = wg & 7;       // (layer, half) group — XCD-affine under round-robin
  const int iwg  = wg >> 3;      // 0..31: which 16-unit slice (= k-block it produces)
  const int l    = grp >> 1;
  const int p    = grp & 1;
  const int tid  = threadIdx.x;
  const int wave = tid >> 6;
  const int lane = tid & 63;

  __shared__ float part[4][32][64];   // 32 KB: per-wave k-split partials, one mtile chunk at a time
  __shared__ float bias_s[64];
  __shared__ float wih1_s[64];
  __shared__ float wlin_s[16];
  __shared__ float red_s[4][64];

  // ---- init: per-wave weight fragments (hi + lo bf16) into registers ----
  s16x8 Whi[2][16], Wlo[2][16];
  {
#pragma unroll
    for (int ji = 0; ji < 16; ++ji) {
      const bool valid = (l > 0) || (ji < 8);
      const float* wsrc = (l == 0 || ji >= 8) ? P.w_hh[l] : P.w_ih[l];
      const int blk = (ji & 7) * 4 + wave;
      const int col = blk * 16 + (lane >> 5) * 8;
#pragma unroll
      for (int m = 0; m < 2; ++m) {
        const int rl = m * 32 + (lane & 31);
        const int grow = (rl >> 4) * 512 + iwg * 16 + (rl & 15);
        s16x8 h8 = {0, 0, 0, 0, 0, 0, 0, 0};
        s16x8 l8 = {0, 0, 0, 0, 0, 0, 0, 0};
        if (valid) {
          const float* s = wsrc + grow * 512 + col;
#pragma unroll
          for (int e = 0; e < 8; ++e) {
            float v = s[e];
            unsigned short hb = f2bf(v);
            h8[e] = (short)hb;
            l8[e] = (short)f2bf(v - bf2f(hb));
          }
        }
        Whi[m][ji] = h8;
        Wlo[m][ji] = l8;
      }
    }
  }
  if (tid < 64) {
    const int rl = tid;
    const int grow = (rl >> 4) * 512 + iwg * 16 + (rl & 15);
    bias_s[rl] = P.b_ih[l][grow] + P.b_hh[l][grow];
    wih1_s[rl] = (l == 0) ? P.w_ih[0][grow] : 0.f;
  }
  if (l == 3 && tid < 16) wlin_s[tid] = P.w_lin[iwg * 16 + tid];
  __syncthreads();

  const int gb = p * 64 + lane;
  const uint32_t kk0 = P.mk[l][0], kk1 = P.mk[l][1];
  float cst[4] = {0.f, 0.f, 0.f, 0.f};

  for (int t = 0; t < TT; ++t) {
    // x load overlaps the flag spin
    float xin = 0.f;
    if (l == 0) xin = P.input[gb * 512 + t];

    // ---------- wait on producer/consumer flags (no fences — data path is sc0/sc1) ----------
    {
      const uint32_t* fp = nullptr;
      if (wave == 0 && l > 0)                     fp = P.flags + (((l - 1) * 2 + p) * TT + t) * 32;
      else if (wave == 1 && t > 0)                fp = P.flags + ((l * 2 + p) * TT + (t - 1)) * 32;
      else if (wave == 2 && l < 3 && t >= 2)      fp = P.flags + (((l + 1) * 2 + p) * TT + (t - 2)) * 32;
      if (fp) {
        while (true) {
          uint32_t v = (lane < 32)
              ? __hip_atomic_load(fp + lane, __ATOMIC_RELAXED, __HIP_MEMORY_SCOPE_AGENT)
              : 1u;
          if (__all(v != 0)) break;
          __builtin_amdgcn_s_sleep(2);
        }
      }
    }
    __syncthreads();
    asm volatile("s_waitcnt vmcnt(0)" ::: "memory");   // drain xin/poll so counted waits are exact

    // ---------- GEMM: gates[64 rows, 64 batch], pipelined sc1 loads ----------
    f32x16 a00 = {0,0,0,0,0,0,0,0,0,0,0,0,0,0,0,0};
    f32x16 a01 = {0,0,0,0,0,0,0,0,0,0,0,0,0,0,0,0};
    f32x16 a10 = {0,0,0,0,0,0,0,0,0,0,0,0,0,0,0,0};
    f32x16 a11 = {0,0,0,0,0,0,0,0,0,0,0,0,0,0,0,0};

    if (l > 0) {
      const unsigned short* below = P.hbuf + (size_t)(((l - 1) * 2 + p) * 2 + (t & 1)) * 32768;
      if (t > 0) {
        const unsigned short* own = P.hbuf + (size_t)((l * 2 + p) * 2 + ((t - 1) & 1)) * 32768;
        run_gemm<16>(below, own, Whi, Wlo, wave, lane, a00, a01, a10, a11);
      } else {
        run_gemm<8>(below, below, Whi, Wlo, wave, lane, a00, a01, a10, a11);
      }
    } else if (t > 0) {
      const unsigned short* own = P.hbuf + (size_t)((0 * 2 + p) * 2 + ((t - 1) & 1)) * 32768;
      run_gemm<8>(own, own, Whi, Wlo, wave, lane, a00, a01, a10, a11);
    }

    // ---------- cross-wave k-split reduction, chunk 0 = rows 0..31 (i,f) ----------
#pragma unroll
    for (int nt = 0; nt < 2; ++nt)
#pragma unroll
      for (int r = 0; r < 16; ++r) {
        const int row = (r & 3) + 8 * (r >> 2) + 4 * (lane >> 5);
        part[wave][row][nt * 32 + (lane & 31)] = (nt == 0) ? a00[r] : a01[r];
      }

    // dropout factors (threefry) in the barrier shadow — independent of GEMM results
    float fac[4];
#pragma unroll
    for (int cc = 0; cc < 4; ++cc) {
      const int gu = iwg * 16 + wave * 4 + cc;
      uint32_t j = ((uint32_t)t * 128u + (uint32_t)gb) * 512u + (uint32_t)gu;
      uint32_t x0 = 0u, x1 = j;
      tf2x32(kk0, kk1, x0, x1);
      fac[cc] = ((x0 ^ x1) & 0x80000000u) ? 0.f : 2.f;
    }
    __syncthreads();
    float si[4], sf[4];
#pragma unroll
    for (int cc = 0; cc < 4; ++cc) {
      const int ul = wave * 4 + cc;
      si[cc] = part[0][ul][lane] + part[1][ul][lane] + part[2][ul][lane] + part[3][ul][lane];
      sf[cc] = part[0][16 + ul][lane] + part[1][16 + ul][lane] + part[2][16 + ul][lane] + part[3][16 + ul][lane];
    }
    __syncthreads();
    // chunk 1 = rows 32..63 (g,o)
#pragma unroll
    for (int nt = 0; nt < 2; ++nt)
#pragma unroll
      for (int r = 0; r < 16; ++r) {
        const int row = (r & 3) + 8 * (r >> 2) + 4 * (lane >> 5);
        part[wave][row][nt * 32 + (lane & 31)] = (nt == 0) ? a10[r] : a11[r];
      }
    __syncthreads();
    float sg[4], so[4];
#pragma unroll
    for (int cc = 0; cc < 4; ++cc) {
      const int ul = wave * 4 + cc;
      sg[cc] = part[0][ul][lane] + part[1][ul][lane] + part[2][ul][lane] + part[3][ul][lane];
      so[cc] = part[0][16 + ul][lane] + part[1][16 + ul][lane] + part[2][16 + ul][lane] + part[3][16 + ul][lane];
    }

    // ---------- elementwise LSTM cell ----------
    float osum = 0.f;
    u16x4 hv;
#pragma unroll
    for (int cc = 0; cc < 4; ++cc) {
      const int ul = wave * 4 + cc;
      float pi = si[cc] + bias_s[ul];
      float pf = sf[cc] + bias_s[16 + ul];
      float pg = sg[cc] + bias_s[32 + ul];
      float po = so[cc] + bias_s[48 + ul];
      if (l == 0) {
        pi += wih1_s[ul] * xin;
        pf += wih1_s[16 + ul] * xin;
        pg += wih1_s[32 + ul] * xin;
        po += wih1_s[48 + ul] * xin;
      }
      float ig = sigm(pi), fg = sigm(pf), gg = tanh_fast(pg), og = sigm(po);
      float cn = fg * cst[cc] + ig * gg;
      cst[cc] = cn;
      float hh = og * tanh_fast(cn) * fac[cc];
      hv[cc] = f2bf(hh);
      if (l == 3) osum += hh * wlin_s[ul];
    }

    // ---------- write h (bf16, MFMA-B blocked layout) via sc1 and publish ----------
    {
      unsigned short* wb = P.hbuf + (size_t)((l * 2 + p) * 2 + (t & 1)) * 32768
          + ((iwg * 2 + (lane >> 5)) * 64 + (wave >> 1) * 32 + (lane & 31)) * 8 + (wave & 1) * 4;
      asm volatile("global_store_dwordx2 %0, %1, off sc0 sc1" :: "v"(wb), "v"(hv) : "memory");
      asm volatile("s_waitcnt vmcnt(0)" ::: "memory");
    }
    __syncthreads();
    if (tid == 0)
      __hip_atomic_store(P.flags + ((l * 2 + p) * TT + t) * 32 + iwg, 1u,
                         __ATOMIC_RELAXED, __HIP_MEMORY_SCOPE_AGENT);

    // ---------- layer-3 projection (off the critical path, after publish) ----------
    if (l == 3) {
      red_s[wave][lane] = osum;
      __syncthreads();
      if (tid < 64) {
        float v = red_s[0][tid] + red_s[1][tid] + red_s[2][tid] + red_s[3][tid];
        if (iwg == 0) v += P.b_lin[0];
        atomicAdd(&P.out[(p * 64 + tid) * 512 + t], v);
      }
    }
  }
}

extern "C" void kernel_launch(void* const* d_in, const int* in_sizes, int n_in,
                              void* d_out, int out_size, void* d_ws, size_t ws_size,
                              hipStream_t stream) {
  (void)in_sizes; (void)n_in; (void)ws_size;
  KParams P;
  P.input = (const float*)d_in[0];
  for (int l = 0; l < 4; ++l) {
    P.w_ih[l] = (const float*)d_in[1 + 4 * l];
    P.w_hh[l] = (const float*)d_in[2 + 4 * l];
    P.b_ih[l] = (const float*)d_in[3 + 4 * l];
    P.b_hh[l] = (const float*)d_in[4 + 4 * l];
  }
  P.w_lin = (const float*)d_in[17];
  P.b_lin = (const float*)d_in[18];
  unsigned char* ws = (unsigned char*)d_ws;
  P.hbuf  = (unsigned short*)ws;                 // 1 MB used
  P.flags = (uint32_t*)(ws + (2u << 20));        // 512 KB (offset kept from R2 — proven in ws_size)
  P.out   = (float*)d_out;

  // subkeys = jax.random.split(key(42), 4) under threefry_partitionable=True
  for (uint32_t i = 0; i < 4; ++i) {
    uint32_t x0 = 0u, x1 = i;
    tf2x32(0u, 42u, x0, x1);
    P.mk[i][0] = x0; P.mk[i][1] = x1;
  }

  hipMemsetAsync(P.flags, 0, 4 * 2 * 512 * 32 * sizeof(uint32_t), stream);
  hipMemsetAsync(d_out, 0, (size_t)out_size * sizeof(float), stream);
  hipLaunchKernelGGL(lstm4, dim3(256), dim3(256), 0, stream, P);
}

// Round 5
// 3507.752 us; speedup vs baseline: 5.4833x; 1.0119x over previous
//
#include <hip/hip_runtime.h>
#include <cstdint>

#define TT 512

typedef float f32x16 __attribute__((ext_vector_type(16)));
typedef short s16x8 __attribute__((ext_vector_type(8)));
typedef unsigned short u16x4 __attribute__((ext_vector_type(4)));

// ---------------- threefry2x32 (exact JAX semantics) ----------------
__host__ __device__ inline void tf2x32(uint32_t k0, uint32_t k1, uint32_t& x0, uint32_t& x1) {
  uint32_t k2 = k0 ^ k1 ^ 0x1BD11BDAu;
#define TF_R(r) { x0 += x1; x1 = (x1 << r) | (x1 >> (32 - r)); x1 ^= x0; }
  x0 += k0; x1 += k1;
  TF_R(13) TF_R(15) TF_R(26) TF_R(6)
  x0 += k1; x1 += k2 + 1u;
  TF_R(17) TF_R(29) TF_R(16) TF_R(24)
  x0 += k2; x1 += k0 + 2u;
  TF_R(13) TF_R(15) TF_R(26) TF_R(6)
  x0 += k0; x1 += k1 + 3u;
  TF_R(17) TF_R(29) TF_R(16) TF_R(24)
  x0 += k1; x1 += k2 + 4u;
  TF_R(13) TF_R(15) TF_R(26) TF_R(6)
  x0 += k2; x1 += k0 + 5u;
#undef TF_R
}

struct KParams {
  const float* input;
  const float* w_ih[4];
  const float* w_hh[4];
  const float* b_ih[4];
  const float* b_hh[4];
  const float* w_lin;
  const float* b_lin;
  unsigned short* hLLC;   // [8][2][32768] bf16 — LLC-coherent copy (sc0 sc1)
  unsigned short* hL2;    // [8][2][32768] bf16 — per-XCD L2 copy (sc0), data only
  uint32_t* fLLC;         // [8][64][32] epoch-ring flags, value = t+1 (LLC)
  uint32_t* xcdtab;       // [256]
  uint32_t* initcnt;      // [1]
  float* out;             // [128][512]
  uint32_t mk[4][2];      // per-layer threefry subkeys (partitionable split)
};

__device__ __forceinline__ unsigned short f2bf(float v) {
  uint32_t u = __float_as_uint(v);
  u += 0x7FFFu + ((u >> 16) & 1u);      // RNE
  return (unsigned short)(u >> 16);
}
__device__ __forceinline__ float bf2f(unsigned short b) {
  return __uint_as_float(((uint32_t)b) << 16);
}
__device__ __forceinline__ float sigm(float x) { return 1.f / (1.f + __expf(-x)); }
__device__ __forceinline__ float tanh_fast(float x) {
  float a = fabsf(x);
  float e = __expf(-2.f * a);
  float r = (1.f - e) / (1.f + e);
  return copysignf(r, x);
}

#define MFMA(A, Bv, C) __builtin_amdgcn_mfma_f32_32x32x16_bf16((A), (Bv), (C), 0, 0, 0)

// counted vmcnt wait (a = pipeline iterations still allowed in flight; 2 loads/iter)
__device__ __forceinline__ void vmwait_dyn(int a) {
  switch (a) {
    case 0: asm volatile("s_waitcnt vmcnt(0)" ::: "memory"); break;
    case 1: asm volatile("s_waitcnt vmcnt(2)" ::: "memory"); break;
    case 2: asm volatile("s_waitcnt vmcnt(4)" ::: "memory"); break;
    case 3: asm volatile("s_waitcnt vmcnt(6)" ::: "memory"); break;
    case 4: asm volatile("s_waitcnt vmcnt(8)" ::: "memory"); break;
    case 5: asm volatile("s_waitcnt vmcnt(10)" ::: "memory"); break;
    case 6: asm volatile("s_waitcnt vmcnt(12)" ::: "memory"); break;
    case 7: asm volatile("s_waitcnt vmcnt(14)" ::: "memory"); break;
    default: asm volatile("s_waitcnt vmcnt(16)" ::: "memory"); break;
  }
  __builtin_amdgcn_sched_barrier(0);
}

#define ISSUE_LLC(s0, s1, ptr) \
  asm volatile("global_load_dwordx4 %0, %2, off sc0 sc1\n\t" \
               "global_load_dwordx4 %1, %2, off offset:1024 sc0 sc1" \
               : "=&v"(s0), "=&v"(s1) : "v"(ptr) : "memory")
#define ISSUE_L2(s0, s1, ptr) \
  asm volatile("global_load_dwordx4 %0, %2, off sc0\n\t" \
               "global_load_dwordx4 %1, %2, off offset:1024 sc0" \
               : "=&v"(s0), "=&v"(s1) : "v"(ptr) : "memory")

// frag i < OWNSTART comes from bufB (always LLC); i >= OWNSTART from bufO (L2 iff OWNL2)
template <int NIT, int OWNSTART, bool OWNL2>
__device__ __forceinline__ void run_gemm(const unsigned short* bufB, const unsigned short* bufO,
                                         const s16x8 (&Whi)[2][16], const s16x8 (&Wlo)[2][16],
                                         int wave, int lane,
                                         f32x16& a00, f32x16& a01, f32x16& a10, f32x16& a11) {
  constexpr int D = 8;
  constexpr int S = D + 1;
  s16x8 st[S][2];
  const int lofs = wave * 1024 + lane * 8;   // blk = (i&7)*4 + wave
#pragma unroll
  for (int i = 0; i < ((NIT < D) ? NIT : D); ++i) {
    const unsigned short* ptr = ((i >= OWNSTART) ? bufO : bufB) + (i & 7) * 4096 + lofs;
    if (i >= OWNSTART && OWNL2) { ISSUE_L2(st[i % S][0], st[i % S][1], ptr); }
    else                        { ISSUE_LLC(st[i % S][0], st[i % S][1], ptr); }
  }
#pragma unroll
  for (int i = 0; i < NIT; ++i) {
    if (i + D < NIT) {
      const int k = i + D;
      const unsigned short* ptr = ((k >= OWNSTART) ? bufO : bufB) + (k & 7) * 4096 + lofs;
      if (k >= OWNSTART && OWNL2) { ISSUE_L2(st[k % S][0], st[k % S][1], ptr); }
      else                        { ISSUE_LLC(st[k % S][0], st[k % S][1], ptr); }
    }
    vmwait_dyn((NIT - 1 - i < D) ? (NIT - 1 - i) : D);
    s16x8 bh0 = st[i % S][0];
    s16x8 bh1 = st[i % S][1];
    a00 = MFMA(Whi[0][i], bh0, a00);
    a10 = MFMA(Whi[1][i], bh0, a10);
    a01 = MFMA(Whi[0][i], bh1, a01);
    a11 = MFMA(Whi[1][i], bh1, a11);
    a00 = MFMA(Wlo[0][i], bh0, a00);
    a10 = MFMA(Wlo[1][i], bh0, a10);
    a01 = MFMA(Wlo[0][i], bh1, a01);
    a11 = MFMA(Wlo[1][i], bh1, a11);
  }
}

// epoch-ring wait: proceed when all 32 flags >= want (values monotone within a launch)
__device__ __forceinline__ void pollLLC(const uint32_t* fp, uint32_t want, int lane) {
  while (true) {
    uint32_t v = __hip_atomic_load(fp + (lane & 31), __ATOMIC_RELAXED, __HIP_MEMORY_SCOPE_AGENT);
    if (__all(v >= want)) break;
    __builtin_amdgcn_s_sleep(1);
  }
}

__global__ __launch_bounds__(256, 1) void lstm4(KParams P) {
  const int wg   = blockIdx.x;
  const int grp  = wg & 7;       // (layer, half) — one XCD per group under round-robin
  const int iwg  = wg >> 3;      // 0..31: which 16-unit slice
  const int l    = grp >> 1;
  const int p    = grp & 1;
  const int tid  = threadIdx.x;
  const int wave = tid >> 6;
  const int lane = tid & 63;

  __shared__ float part[4][64][64];   // 64 KB: per-wave k-split partials, single phase
  __shared__ float bias_s[64];
  __shared__ float wih1_s[64];
  __shared__ float wlin_s[16];
  __shared__ float red_s[4][64];
  __shared__ uint32_t xs[8];
  __shared__ uint32_t barflag;

  // ---- XCD identity probe (hwreg 20 = XCC_ID on gfx950; wrong field -> check fails -> fallback)
  uint32_t xcd;
  asm volatile("s_getreg_b32 %0, hwreg(20, 0, 4)" : "=s"(xcd));

  if (tid == 0) {
    __hip_atomic_store(&P.xcdtab[wg], xcd, __ATOMIC_RELAXED, __HIP_MEMORY_SCOPE_AGENT);
    asm volatile("s_waitcnt vmcnt(0)" ::: "memory");
    __hip_atomic_fetch_add(P.initcnt, 1u, __ATOMIC_RELAXED, __HIP_MEMORY_SCOPE_AGENT);
  }

  // ---- weight fragments (hi + lo bf16) into registers (overlaps other WGs' init)
  s16x8 Whi[2][16], Wlo[2][16];
  {
#pragma unroll
    for (int ji = 0; ji < 16; ++ji) {
      const bool valid = (l > 0) || (ji < 8);
      const float* wsrc = (l == 0 || ji >= 8) ? P.w_hh[l] : P.w_ih[l];
      const int blk = (ji & 7) * 4 + wave;
      const int col = blk * 16 + (lane >> 5) * 8;
#pragma unroll
      for (int m = 0; m < 2; ++m) {
        const int rl = m * 32 + (lane & 31);
        const int grow = (rl >> 4) * 512 + iwg * 16 + (rl & 15);
        s16x8 h8 = {0, 0, 0, 0, 0, 0, 0, 0};
        s16x8 l8 = {0, 0, 0, 0, 0, 0, 0, 0};
        if (valid) {
          const float* s = wsrc + grow * 512 + col;
#pragma unroll
          for (int e = 0; e < 8; ++e) {
            float v = s[e];
            unsigned short hb = f2bf(v);
            h8[e] = (short)hb;
            l8[e] = (short)f2bf(v - bf2f(hb));
          }
        }
        Whi[m][ji] = h8;
        Wlo[m][ji] = l8;
      }
    }
  }
  if (tid < 64) {
    const int rl = tid;
    const int grow = (rl >> 4) * 512 + iwg * 16 + (rl & 15);
    bias_s[rl] = P.b_ih[l][grow] + P.b_hh[l][grow];
    wih1_s[rl] = (l == 0) ? P.w_ih[0][grow] : 0.f;
  }
  if (l == 3 && tid < 16) wlin_s[tid] = P.w_lin[iwg * 16 + tid];

  // ---- bounded grid init barrier (timeout -> LLC-only fallback, never hang)
  if (tid == 0) {
    uint32_t okv = 1u, tries = 0u;
    while (__hip_atomic_load(P.initcnt, __ATOMIC_RELAXED, __HIP_MEMORY_SCOPE_AGENT) < 256u) {
      __builtin_amdgcn_s_sleep(8);
      if (++tries > (1u << 17)) { okv = 0u; break; }   // ~30+ ms >> init time
    }
    barflag = okv;
  }
  __syncthreads();
  const bool bar_ok = (barflag != 0u);

  // ---- XCD-mapping verification (thread tid checks WG tid's entry)
  uint32_t va = __hip_atomic_load(&P.xcdtab[tid], __ATOMIC_RELAXED, __HIP_MEMORY_SCOPE_AGENT);
  uint32_t vb = __hip_atomic_load(&P.xcdtab[tid & 7], __ATOMIC_RELAXED, __HIP_MEMORY_SCOPE_AGENT);
  int ok1 = __syncthreads_and((va == vb) ? 1 : 0);
  if (tid < 8) xs[tid] = vb;
  __syncthreads();
  bool dis = true;
#pragma unroll
  for (int a = 0; a < 8; ++a)
#pragma unroll
    for (int b = a + 1; b < 8; ++b)
      if (xs[a] == xs[b]) dis = false;
  const bool l2ok = bar_ok && (ok1 != 0) && dis;
  __syncthreads();

  const int gb = p * 64 + lane;
  const uint32_t kk0 = P.mk[l][0], kk1 = P.mk[l][1];
  float cst[4] = {0.f, 0.f, 0.f, 0.f};

  for (int t = 0; t < TT; ++t) {
    float xin = 0.f;
    if (l == 0) xin = P.input[gb * 512 + t];

    // ---------- waits (epoch-ring LLC flags): wave0=below(t), wave1=own(t-1), wave2=above(t-2) ----------
    if (wave == 0 && l > 0) {
      pollLLC(P.fLLC + ((size_t)((l - 1) * 2 + p) * 64 + (t & 63)) * 32, (uint32_t)(t + 1), lane);
    } else if (wave == 1 && t > 0) {
      pollLLC(P.fLLC + ((size_t)grp * 64 + ((t - 1) & 63)) * 32, (uint32_t)t, lane);
    } else if (wave == 2 && l < 3 && t >= 2) {
      pollLLC(P.fLLC + ((size_t)((l + 1) * 2 + p) * 64 + ((t - 2) & 63)) * 32, (uint32_t)(t - 1), lane);
    }
    __syncthreads();
    asm volatile("s_waitcnt vmcnt(0)" ::: "memory");   // drain xin/polls: counted waits exact

    // ---------- GEMM ----------
    f32x16 a00 = {0,0,0,0,0,0,0,0,0,0,0,0,0,0,0,0};
    f32x16 a01 = {0,0,0,0,0,0,0,0,0,0,0,0,0,0,0,0};
    f32x16 a10 = {0,0,0,0,0,0,0,0,0,0,0,0,0,0,0,0};
    f32x16 a11 = {0,0,0,0,0,0,0,0,0,0,0,0,0,0,0,0};

    const unsigned short* pB    = P.hLLC + (size_t)(((l - 1) * 2 + p) * 2 + (t & 1)) * 32768;
    const unsigned short* pOL2  = P.hL2  + (size_t)(grp * 2 + ((t - 1) & 1)) * 32768;
    const unsigned short* pOLLC = P.hLLC + (size_t)(grp * 2 + ((t - 1) & 1)) * 32768;

    if (l > 0) {
      if (t > 0) {
        if (l2ok) run_gemm<16, 8, true >(pB, pOL2,  Whi, Wlo, wave, lane, a00, a01, a10, a11);
        else      run_gemm<16, 8, false>(pB, pOLLC, Whi, Wlo, wave, lane, a00, a01, a10, a11);
      } else {
        run_gemm<8, 8, false>(pB, pB, Whi, Wlo, wave, lane, a00, a01, a10, a11);
      }
    } else if (t > 0) {
      if (l2ok) run_gemm<8, 0, true >(pOL2,  pOL2,  Whi, Wlo, wave, lane, a00, a01, a10, a11);
      else      run_gemm<8, 0, false>(pOLLC, pOLLC, Whi, Wlo, wave, lane, a00, a01, a10, a11);
    }

    // ---------- single-phase cross-wave k-split reduction ----------
#pragma unroll
    for (int r = 0; r < 16; ++r) {
      const int row = (r & 3) + 8 * (r >> 2) + 4 * (lane >> 5);
      const int cl = lane & 31;
      part[wave][row][cl]           = a00[r];
      part[wave][row][32 + cl]      = a01[r];
      part[wave][32 + row][cl]      = a10[r];
      part[wave][32 + row][32 + cl] = a11[r];
    }

    // dropout factors (threefry) in the barrier shadow
    float fac[4];
#pragma unroll
    for (int cc = 0; cc < 4; ++cc) {
      const int gu = iwg * 16 + wave * 4 + cc;
      uint32_t j = ((uint32_t)t * 128u + (uint32_t)gb) * 512u + (uint32_t)gu;
      uint32_t x0 = 0u, x1 = j;
      tf2x32(kk0, kk1, x0, x1);
      fac[cc] = ((x0 ^ x1) & 0x80000000u) ? 0.f : 2.f;
    }
    __syncthreads();

    float si[4], sf[4], sg[4], so[4];
#pragma unroll
    for (int cc = 0; cc < 4; ++cc) {
      const int ul = wave * 4 + cc;
      si[cc] = part[0][ul][lane]      + part[1][ul][lane]      + part[2][ul][lane]      + part[3][ul][lane];
      sf[cc] = part[0][16 + ul][lane] + part[1][16 + ul][lane] + part[2][16 + ul][lane] + part[3][16 + ul][lane];
      sg[cc] = part[0][32 + ul][lane] + part[1][32 + ul][lane] + part[2][32 + ul][lane] + part[3][32 + ul][lane];
      so[cc] = part[0][48 + ul][lane] + part[1][48 + ul][lane] + part[2][48 + ul][lane] + part[3][48 + ul][lane];
    }

    // ---------- elementwise LSTM cell ----------
    float osum = 0.f;
    u16x4 hv;
#pragma unroll
    for (int cc = 0; cc < 4; ++cc) {
      const int ul = wave * 4 + cc;
      float pi = si[cc] + bias_s[ul];
      float pf = sf[cc] + bias_s[16 + ul];
      float pg = sg[cc] + bias_s[32 + ul];
      float po = so[cc] + bias_s[48 + ul];
      if (l == 0) {
        pi += wih1_s[ul] * xin;
        pf += wih1_s[16 + ul] * xin;
        pg += wih1_s[32 + ul] * xin;
        po += wih1_s[48 + ul] * xin;
      }
      float ig = sigm(pi), fg = sigm(pf), gg = tanh_fast(pg), og = sigm(po);
      float cn = fg * cst[cc] + ig * gg;
      cst[cc] = cn;
      float hh = og * tanh_fast(cn) * fac[cc];
      hv[cc] = f2bf(hh);
      if (l == 3) osum += hh * wlin_s[ul];
    }

    // ---------- unconditional dual h store (LLC + per-XCD L2) + publish ----------
    {
      const int elem = ((iwg * 2 + (lane >> 5)) * 64 + (wave >> 1) * 32 + (lane & 31)) * 8 + (wave & 1) * 4;
      unsigned short* wLLC = P.hLLC + (size_t)(grp * 2 + (t & 1)) * 32768 + elem;
      unsigned short* wL2  = P.hL2  + (size_t)(grp * 2 + (t & 1)) * 32768 + elem;
      asm volatile("global_store_dwordx2 %0, %1, off sc0 sc1" :: "v"(wLLC), "v"(hv) : "memory");
      asm volatile("global_store_dwordx2 %0, %1, off sc0" :: "v"(wL2), "v"(hv) : "memory");
      asm volatile("s_waitcnt vmcnt(0)" ::: "memory");
    }
    __syncthreads();
    if (tid == 0)
      __hip_atomic_store(P.fLLC + ((size_t)grp * 64 + (t & 63)) * 32 + iwg, (uint32_t)(t + 1),
                         __ATOMIC_RELAXED, __HIP_MEMORY_SCOPE_AGENT);

    // ---------- layer-3 projection (after publish) ----------
    if (l == 3) {
      red_s[wave][lane] = osum;
      __syncthreads();
      if (tid < 64) {
        float v = red_s[0][tid] + red_s[1][tid] + red_s[2][tid] + red_s[3][tid];
        if (iwg == 0) v += P.b_lin[0];
        atomicAdd(&P.out[(p * 64 + tid) * 512 + t], v);
      }
    }
  }
}

extern "C" void kernel_launch(void* const* d_in, const int* in_sizes, int n_in,
                              void* d_out, int out_size, void* d_ws, size_t ws_size,
                              hipStream_t stream) {
  (void)in_sizes; (void)n_in; (void)ws_size;
  KParams P;
  P.input = (const float*)d_in[0];
  for (int l = 0; l < 4; ++l) {
    P.w_ih[l] = (const float*)d_in[1 + 4 * l];
    P.w_hh[l] = (const float*)d_in[2 + 4 * l];
    P.b_ih[l] = (const float*)d_in[3 + 4 * l];
    P.b_hh[l] = (const float*)d_in[4 + 4 * l];
  }
  P.w_lin = (const float*)d_in[17];
  P.b_lin = (const float*)d_in[18];
  unsigned char* ws = (unsigned char*)d_ws;
  P.hLLC    = (unsigned short*)(ws);                          // 1 MB   [8][2][32768]
  P.hL2     = (unsigned short*)(ws + (1u << 20));             // 1 MB   [8][2][32768]
  P.fLLC    = (uint32_t*)(ws + (2u << 20));                   // 64 KB  [8][64][32]
  P.xcdtab  = (uint32_t*)(ws + (2u << 20) + (64u << 10));     // 1 KB
  P.initcnt = (uint32_t*)(ws + (2u << 20) + (64u << 10) + 1024);
  P.out     = (float*)d_out;
  // total ws use: 2 MB + 66 KB  (<= 2.62 MB proven by R2/R3)

  // subkeys = jax.random.split(key(42), 4) under threefry_partitionable=True
  for (uint32_t i = 0; i < 4; ++i) {
    uint32_t x0 = 0u, x1 = i;
    tf2x32(0u, 42u, x0, x1);
    P.mk[i][0] = x0; P.mk[i][1] = x1;
  }

  hipMemsetAsync(P.fLLC, 0, 8 * 64 * 32 * sizeof(uint32_t), stream);
  hipMemsetAsync(P.xcdtab, 0, 2048, stream);                  // xcdtab + initcnt
  hipMemsetAsync(d_out, 0, (size_t)out_size * sizeof(float), stream);
  hipLaunchKernelGGL(lstm4, dim3(256), dim3(256), 0, stream, P);
}